// Round 14
// baseline (430.295 us; speedup 1.0000x reference)
//
#include <hip/hip_runtime.h>
#include <stdint.h>

// irreps linear: 128x0e+128x1o+128x2e, per-block y[z,w,i] = a * sum_u W[u,w] x[z,u,i]
// r14 = r13 (fused full-row WGs, plain stores, best 191.1us) with grid 512:
// TWO 1024-thread WGs per CU (LDS 2x73728=147456 <= 163840; VGPR 60 <= 64 cap
// at 8 waves/SIMD). With 1 WG/CU the memory system idles during each WG's
// barrier/store/stage phases; a phase-independent co-resident WG fills them.
// Structure: one WG owns 16 complete rows per tile (contiguous 73.7KB read +
// write), W in regs, dbuf LDS, prefetch before MFMA, dense per-lane plain
// stores, one __syncthreads per tile.

#define NROWS 100000
#define ROWLEN 1152

typedef __attribute__((ext_vector_type(8))) short bf16x8;
typedef __attribute__((ext_vector_type(4))) float f32x4;
typedef __attribute__((ext_vector_type(4))) ushort u16x4;
typedef float f32x4u __attribute__((ext_vector_type(4), aligned(4)));
typedef float f32x2u __attribute__((ext_vector_type(2), aligned(4)));

__device__ __forceinline__ ushort f2b(float f) {
  union { float f; uint32_t u; } v; v.f = f;
  uint32_t r = v.u + 0x7FFFu + ((v.u >> 16) & 1u);  // RNE; inputs finite
  return (ushort)(r >> 16);
}

constexpr int TM     = 16;
constexpr int NTILES = NROWS / TM;   // 6250 exactly -> no guards anywhere
constexpr int NWGS   = 512;          // 2 WGs/CU
constexpr int BUFB   = 144 * 256;    // 36864 B: 144 m-rows (16 D1 + 48 D3 + 80 D5)
constexpr float ALPHA = 0.088388347648318447f;  // 128^-0.5

// LDS byte for (m-row, 4-u chunk cc in 0..31), 8B granule; 16B-chunk XOR swizzle.
__device__ __forceinline__ int lbyte8(int m, int cc) {
  return m * 256 + ((((cc >> 1) ^ (m & 7)) << 4) | ((cc & 1) << 3));
}

// ---- staging: class A (tid<512): one D1 group + one D3 group; class B: one D5
// group. Group g: row szl = g>>5, u-chunk cc = g&31.
__device__ __forceinline__ void stage_load(const float* __restrict__ x, int t,
                                           bool clb, int szl, int scc,
                                           f32x4 (&vf)[5])
{
  const float* row = x + (size_t)(t * TM + szl) * ROWLEN;
  if (!clb) {
    vf[0] = *(const f32x4*)(row + scc * 4);            // D1: u = 4cc..4cc+3
    const float* r3 = row + 128 + scc * 12;            // D3: 12 floats
    vf[1] = *(const f32x4*)(r3);
    vf[2] = *(const f32x4*)(r3 + 4);
    vf[3] = *(const f32x4*)(r3 + 8);
  } else {
    const float* r5 = row + 512 + scc * 20;            // D5: 20 floats
    #pragma unroll
    for (int j = 0; j < 5; ++j) vf[j] = *(const f32x4*)(r5 + 4 * j);
  }
}

__device__ __forceinline__ void stage_write(char* __restrict__ buf, bool clb,
                                            int szl, int scc, f32x4 (&vf)[5])
{
  if (!clb) {
    u16x4 p1;
    #pragma unroll
    for (int k = 0; k < 4; ++k) p1[k] = f2b(vf[0][k]);
    *(u16x4*)(buf + lbyte8(szl, scc)) = p1;            // D1: m = szl
    #pragma unroll
    for (int i = 0; i < 3; ++i) {                      // D3: m = 16 + i*16 + szl
      u16x4 pk;
      #pragma unroll
      for (int u = 0; u < 4; ++u) {
        int k = 3 * u + i;                             // compile-time
        pk[u] = f2b(vf[1 + (k >> 2)][k & 3]);
      }
      *(u16x4*)(buf + lbyte8(16 + i * 16 + szl, scc)) = pk;
    }
  } else {
    #pragma unroll
    for (int i = 0; i < 5; ++i) {                      // D5: m = 64 + i*16 + szl
      u16x4 pk;
      #pragma unroll
      for (int u = 0; u < 4; ++u) {
        int k = 5 * u + i;                             // compile-time
        pk[u] = f2b(vf[k >> 2][k & 3]);
      }
      *(u16x4*)(buf + lbyte8(64 + i * 16 + szl, scc)) = pk;
    }
  }
}

__global__ __launch_bounds__(1024, 8)
void linear_irreps_kernel(const float* __restrict__ x, const float* __restrict__ w,
                          float* __restrict__ out)
{
  __shared__ __align__(16) char lds[2 * BUFB];         // 73728 B

  const int tid  = threadIdx.x;
  const int lane = tid & 63;
  const int wv   = tid >> 6;            // 0..15
  const int l15  = lane & 15;
  const int kq   = (lane >> 4) & 3;
  const int kr   = kq << 3;
  const int mx7  = l15 & 7;             // (m & 7) for all m = base16 + l15
  const int h    = wv & 1;              // 0: D1+D3 m-tiles, 1: D5 m-tiles
  const int n    = ((wv >> 1) << 4) + l15;   // out/W column 0..127
  const bool clb = tid >= 512;
  const int sg   = clb ? tid - 512 : tid;
  const int szl  = sg >> 5;
  const int scc  = sg & 31;

  // ---- W -> registers once (ALPHA folded). h0: D1+D3 blocks; h1: D5 block.
  bf16x8 bfr[2][4];
  if (h == 0) {
    #pragma unroll
    for (int ks = 0; ks < 4; ++ks)
      #pragma unroll
      for (int j = 0; j < 8; ++j) {
        bfr[0][ks][j] = (short)f2b(w[(ks * 32 + kr + j) * 128 + n] * ALPHA);
        bfr[1][ks][j] = (short)f2b(w[16384 + (ks * 32 + kr + j) * 128 + n] * ALPHA);
      }
  } else {
    #pragma unroll
    for (int ks = 0; ks < 4; ++ks)
      #pragma unroll
      for (int j = 0; j < 8; ++j)
        bfr[0][ks][j] = (short)f2b(w[32768 + (ks * 32 + kr + j) * 128 + n] * ALPHA);
  }

  // ---- prologue: stage tile t0 ----
  const int t0 = blockIdx.x;
  f32x4 vf[5];
  if (t0 < NTILES) {
    stage_load(x, t0, clb, szl, scc, vf);
    stage_write(lds, clb, szl, scc, vf);
  }
  __syncthreads();

  int cur = 0;
  for (int t = t0; t < NTILES; t += NWGS) {
    char* bc = lds + (cur ? BUFB : 0);
    char* bn = lds + (cur ? 0 : BUFB);
    const int tn = t + NWGS;
    const bool have = tn < NTILES;

    // 1. issue next tile's global loads (hide under MFMA)
    if (have) stage_load(x, tn, clb, szl, scc, vf);

    // 2. MFMA on current buffer
    f32x4 acc[5];
    #pragma unroll
    for (int i = 0; i < 5; ++i) acc[i] = f32x4{0.f, 0.f, 0.f, 0.f};
    if (h == 0) {
      #pragma unroll
      for (int ks = 0; ks < 4; ++ks) {
        const int cb = ((ks * 4 + kq) ^ mx7) << 4;
        bf16x8 a0 = *(const bf16x8*)(bc + (l15)       * 256 + cb);
        bf16x8 a1 = *(const bf16x8*)(bc + (16  + l15) * 256 + cb);
        bf16x8 a2 = *(const bf16x8*)(bc + (32  + l15) * 256 + cb);
        bf16x8 a3 = *(const bf16x8*)(bc + (48  + l15) * 256 + cb);
        acc[0] = __builtin_amdgcn_mfma_f32_16x16x32_bf16(a0, bfr[0][ks], acc[0], 0, 0, 0);
        acc[1] = __builtin_amdgcn_mfma_f32_16x16x32_bf16(a1, bfr[1][ks], acc[1], 0, 0, 0);
        acc[2] = __builtin_amdgcn_mfma_f32_16x16x32_bf16(a2, bfr[1][ks], acc[2], 0, 0, 0);
        acc[3] = __builtin_amdgcn_mfma_f32_16x16x32_bf16(a3, bfr[1][ks], acc[3], 0, 0, 0);
      }
    } else {
      #pragma unroll
      for (int ks = 0; ks < 4; ++ks) {
        const int cb = ((ks * 4 + kq) ^ mx7) << 4;
        #pragma unroll
        for (int i = 0; i < 5; ++i) {
          bf16x8 a = *(const bf16x8*)(bc + (64 + i * 16 + l15) * 256 + cb);
          acc[i] = __builtin_amdgcn_mfma_f32_16x16x32_bf16(a, bfr[0][ks], acc[i], 0, 0, 0);
        }
      }
    }

    // 3. convert + LDS-write next tile (loads have landed)
    if (have) stage_write(bn, clb, szl, scc, vf);

    // 4. store tile t (dense per-lane spans, plain stores)
    const int z0 = t * TM;
    if (h == 0) {
      #pragma unroll
      for (int r = 0; r < 4; ++r) {
        int z = z0 + (kq << 2) + r;
        float* orow = out + (size_t)z * ROWLEN;
        orow[n] = acc[0][r];
        f32x2u v2 = { acc[1][r], acc[2][r] };
        *(f32x2u*)(orow + 128 + n * 3) = v2;
        orow[128 + n * 3 + 2] = acc[3][r];
      }
    } else {
      #pragma unroll
      for (int r = 0; r < 4; ++r) {
        int z = z0 + (kq << 2) + r;
        float* orow = out + (size_t)z * ROWLEN;
        f32x4u v4 = { acc[0][r], acc[1][r], acc[2][r], acc[3][r] };
        *(f32x4u*)(orow + 512 + n * 5) = v4;
        orow[512 + n * 5 + 4] = acc[4][r];
      }
    }

    __syncthreads();
    cur ^= 1;
  }
}

extern "C" void kernel_launch(void* const* d_in, const int* in_sizes, int n_in,
                              void* d_out, int out_size, void* d_ws, size_t ws_size,
                              hipStream_t stream) {
  const float* x = (const float*)d_in[0];
  const float* w = (const float*)d_in[1];
  float* out = (float*)d_out;
  (void)in_sizes; (void)n_in; (void)out_size; (void)d_ws; (void)ws_size;
  dim3 grid(NWGS);
  dim3 block(1024);
  hipLaunchKernelGGL(linear_irreps_kernel, grid, block, 0, stream, x, w, out);
}

// Round 15
// 193.482 us; speedup vs baseline: 2.2239x; 2.2239x over previous
//
#include <hip/hip_runtime.h>
#include <stdint.h>

// irreps linear: 128x0e+128x1o+128x2e, per-block y[z,w,i] = a * sum_u W[u,w] x[z,u,i]
// r15 = r13 (fused full-row WGs, plain stores, best 191.1us) + grid 512.
// launch_bounds stays (1024,4): r13's compiled VGPR=60 already fits 8 waves/
// SIMD (<=64) and 2x36.9KB-dbuf LDS fits 160KiB, so the scheduler can place
// TWO phase-independent WGs per CU without constraining the allocator.
// (r14's (1024,8) forced VGPR 32 -> spills -> 430us. Lesson: give the HW the
// occupancy option, never force the allocator.)

#define NROWS 100000
#define ROWLEN 1152

typedef __attribute__((ext_vector_type(8))) short bf16x8;
typedef __attribute__((ext_vector_type(4))) float f32x4;
typedef __attribute__((ext_vector_type(4))) ushort u16x4;
typedef float f32x4u __attribute__((ext_vector_type(4), aligned(4)));
typedef float f32x2u __attribute__((ext_vector_type(2), aligned(4)));

__device__ __forceinline__ ushort f2b(float f) {
  union { float f; uint32_t u; } v; v.f = f;
  uint32_t r = v.u + 0x7FFFu + ((v.u >> 16) & 1u);  // RNE; inputs finite
  return (ushort)(r >> 16);
}

constexpr int TM     = 16;
constexpr int NTILES = NROWS / TM;   // 6250 exactly -> no guards anywhere
constexpr int NWGS   = 512;          // 2 WGs/CU (scheduler's choice, not forced)
constexpr int BUFB   = 144 * 256;    // 36864 B: 144 m-rows (16 D1 + 48 D3 + 80 D5)
constexpr float ALPHA = 0.088388347648318447f;  // 128^-0.5

// LDS byte for (m-row, 4-u chunk cc in 0..31), 8B granule; 16B-chunk XOR swizzle.
__device__ __forceinline__ int lbyte8(int m, int cc) {
  return m * 256 + ((((cc >> 1) ^ (m & 7)) << 4) | ((cc & 1) << 3));
}

// ---- staging: class A (tid<512): one D1 group + one D3 group; class B: one D5
// group. Group g: row szl = g>>5, u-chunk cc = g&31.
__device__ __forceinline__ void stage_load(const float* __restrict__ x, int t,
                                           bool clb, int szl, int scc,
                                           f32x4 (&vf)[5])
{
  const float* row = x + (size_t)(t * TM + szl) * ROWLEN;
  if (!clb) {
    vf[0] = *(const f32x4*)(row + scc * 4);            // D1: u = 4cc..4cc+3
    const float* r3 = row + 128 + scc * 12;            // D3: 12 floats
    vf[1] = *(const f32x4*)(r3);
    vf[2] = *(const f32x4*)(r3 + 4);
    vf[3] = *(const f32x4*)(r3 + 8);
  } else {
    const float* r5 = row + 512 + scc * 20;            // D5: 20 floats
    #pragma unroll
    for (int j = 0; j < 5; ++j) vf[j] = *(const f32x4*)(r5 + 4 * j);
  }
}

__device__ __forceinline__ void stage_write(char* __restrict__ buf, bool clb,
                                            int szl, int scc, f32x4 (&vf)[5])
{
  if (!clb) {
    u16x4 p1;
    #pragma unroll
    for (int k = 0; k < 4; ++k) p1[k] = f2b(vf[0][k]);
    *(u16x4*)(buf + lbyte8(szl, scc)) = p1;            // D1: m = szl
    #pragma unroll
    for (int i = 0; i < 3; ++i) {                      // D3: m = 16 + i*16 + szl
      u16x4 pk;
      #pragma unroll
      for (int u = 0; u < 4; ++u) {
        int k = 3 * u + i;                             // compile-time
        pk[u] = f2b(vf[1 + (k >> 2)][k & 3]);
      }
      *(u16x4*)(buf + lbyte8(16 + i * 16 + szl, scc)) = pk;
    }
  } else {
    #pragma unroll
    for (int i = 0; i < 5; ++i) {                      // D5: m = 64 + i*16 + szl
      u16x4 pk;
      #pragma unroll
      for (int u = 0; u < 4; ++u) {
        int k = 5 * u + i;                             // compile-time
        pk[u] = f2b(vf[k >> 2][k & 3]);
      }
      *(u16x4*)(buf + lbyte8(64 + i * 16 + szl, scc)) = pk;
    }
  }
}

__global__ __launch_bounds__(1024, 4)
void linear_irreps_kernel(const float* __restrict__ x, const float* __restrict__ w,
                          float* __restrict__ out)
{
  __shared__ __align__(16) char lds[2 * BUFB];         // 73728 B

  const int tid  = threadIdx.x;
  const int lane = tid & 63;
  const int wv   = tid >> 6;            // 0..15
  const int l15  = lane & 15;
  const int kq   = (lane >> 4) & 3;
  const int kr   = kq << 3;
  const int mx7  = l15 & 7;             // (m & 7) for all m = base16 + l15
  const int h    = wv & 1;              // 0: D1+D3 m-tiles, 1: D5 m-tiles
  const int n    = ((wv >> 1) << 4) + l15;   // out/W column 0..127
  const bool clb = tid >= 512;
  const int sg   = clb ? tid - 512 : tid;
  const int szl  = sg >> 5;
  const int scc  = sg & 31;

  // ---- W -> registers once (ALPHA folded). h0: D1+D3 blocks; h1: D5 block.
  bf16x8 bfr[2][4];
  if (h == 0) {
    #pragma unroll
    for (int ks = 0; ks < 4; ++ks)
      #pragma unroll
      for (int j = 0; j < 8; ++j) {
        bfr[0][ks][j] = (short)f2b(w[(ks * 32 + kr + j) * 128 + n] * ALPHA);
        bfr[1][ks][j] = (short)f2b(w[16384 + (ks * 32 + kr + j) * 128 + n] * ALPHA);
      }
  } else {
    #pragma unroll
    for (int ks = 0; ks < 4; ++ks)
      #pragma unroll
      for (int j = 0; j < 8; ++j)
        bfr[0][ks][j] = (short)f2b(w[32768 + (ks * 32 + kr + j) * 128 + n] * ALPHA);
  }

  // ---- prologue: stage tile t0 ----
  const int t0 = blockIdx.x;
  f32x4 vf[5];
  if (t0 < NTILES) {
    stage_load(x, t0, clb, szl, scc, vf);
    stage_write(lds, clb, szl, scc, vf);
  }
  __syncthreads();

  int cur = 0;
  for (int t = t0; t < NTILES; t += NWGS) {
    char* bc = lds + (cur ? BUFB : 0);
    char* bn = lds + (cur ? 0 : BUFB);
    const int tn = t + NWGS;
    const bool have = tn < NTILES;

    // 1. issue next tile's global loads (hide under MFMA)
    if (have) stage_load(x, tn, clb, szl, scc, vf);

    // 2. MFMA on current buffer
    f32x4 acc[5];
    #pragma unroll
    for (int i = 0; i < 5; ++i) acc[i] = f32x4{0.f, 0.f, 0.f, 0.f};
    if (h == 0) {
      #pragma unroll
      for (int ks = 0; ks < 4; ++ks) {
        const int cb = ((ks * 4 + kq) ^ mx7) << 4;
        bf16x8 a0 = *(const bf16x8*)(bc + (l15)       * 256 + cb);
        bf16x8 a1 = *(const bf16x8*)(bc + (16  + l15) * 256 + cb);
        bf16x8 a2 = *(const bf16x8*)(bc + (32  + l15) * 256 + cb);
        bf16x8 a3 = *(const bf16x8*)(bc + (48  + l15) * 256 + cb);
        acc[0] = __builtin_amdgcn_mfma_f32_16x16x32_bf16(a0, bfr[0][ks], acc[0], 0, 0, 0);
        acc[1] = __builtin_amdgcn_mfma_f32_16x16x32_bf16(a1, bfr[1][ks], acc[1], 0, 0, 0);
        acc[2] = __builtin_amdgcn_mfma_f32_16x16x32_bf16(a2, bfr[1][ks], acc[2], 0, 0, 0);
        acc[3] = __builtin_amdgcn_mfma_f32_16x16x32_bf16(a3, bfr[1][ks], acc[3], 0, 0, 0);
      }
    } else {
      #pragma unroll
      for (int ks = 0; ks < 4; ++ks) {
        const int cb = ((ks * 4 + kq) ^ mx7) << 4;
        #pragma unroll
        for (int i = 0; i < 5; ++i) {
          bf16x8 a = *(const bf16x8*)(bc + (64 + i * 16 + l15) * 256 + cb);
          acc[i] = __builtin_amdgcn_mfma_f32_16x16x32_bf16(a, bfr[0][ks], acc[i], 0, 0, 0);
        }
      }
    }

    // 3. convert + LDS-write next tile (loads have landed)
    if (have) stage_write(bn, clb, szl, scc, vf);

    // 4. store tile t (dense per-lane spans, plain stores)
    const int z0 = t * TM;
    if (h == 0) {
      #pragma unroll
      for (int r = 0; r < 4; ++r) {
        int z = z0 + (kq << 2) + r;
        float* orow = out + (size_t)z * ROWLEN;
        orow[n] = acc[0][r];
        f32x2u v2 = { acc[1][r], acc[2][r] };
        *(f32x2u*)(orow + 128 + n * 3) = v2;
        orow[128 + n * 3 + 2] = acc[3][r];
      }
    } else {
      #pragma unroll
      for (int r = 0; r < 4; ++r) {
        int z = z0 + (kq << 2) + r;
        float* orow = out + (size_t)z * ROWLEN;
        f32x4u v4 = { acc[0][r], acc[1][r], acc[2][r], acc[3][r] };
        *(f32x4u*)(orow + 512 + n * 5) = v4;
        orow[512 + n * 5 + 4] = acc[4][r];
      }
    }

    __syncthreads();
    cur ^= 1;
  }
}

extern "C" void kernel_launch(void* const* d_in, const int* in_sizes, int n_in,
                              void* d_out, int out_size, void* d_ws, size_t ws_size,
                              hipStream_t stream) {
  const float* x = (const float*)d_in[0];
  const float* w = (const float*)d_in[1];
  float* out = (float*)d_out;
  (void)in_sizes; (void)n_in; (void)out_size; (void)d_ws; (void)ws_size;
  dim3 grid(NWGS);
  dim3 block(1024);
  hipLaunchKernelGGL(linear_irreps_kernel, grid, block, 0, stream, x, w, out);
}